// Round 9
// baseline (96.304 us; speedup 1.0000x reference)
//
#include <hip/hip_runtime.h>
#include <math.h>

#define NT 256
#define NB 2048
#define AST 104        // A row stride (halfwords); 66 rows; col a <-> image col w0c+a
#define BST 102        // B row stride (halfwords); 32 rows; col j <-> region col j (0..97)

// f32 -> bf16 bits, round-to-nearest-even (inputs finite, >= 0)
__device__ __forceinline__ unsigned short f2b(float f) {
    unsigned int u = __float_as_uint(f);
    u += 0x7FFFu + ((u >> 16) & 1u);
    return (unsigned short)(u >> 16);
}

__global__ __launch_bounds__(NT, 5)
void dark_fused(const float* __restrict__ x, int* __restrict__ cnt,
                float* __restrict__ part, float* __restrict__ out) {
    __shared__ unsigned short A[66 * AST];   // 13728 B: bf16 bits of m=min_c(x); pad=1.0
    __shared__ unsigned short B[32 * BST];   // 6528 B: bf16 bits of vertical 35-min
    __shared__ float red[4];                 // ~20.3 KB total -> 5 blocks/CU
    __shared__ int   last;

    const int tid = threadIdx.x;
    const int bid = blockIdx.x;
    // XCD swizzle (R7's proven mapping): XCD k -> 256 consecutive tiles = images 2k,2k+1
    const int swz = (bid & 7) * 256 + (bid >> 3);
    const int b   = swz >> 7;                // 128 tiles per image (16 ty x 8 tx)
    const int rem = swz & 127;
    const int ty  = rem >> 3;                // 32-row bands
    const int tx  = rem & 7;                 // 64-col bands
    const int h0  = ty * 32 - 17;            // region row k <-> image row h0+k, k in [0,66)
    const int w0c = tx * 64 - 20;            // A col a <-> image col w0c+a (f4-aligned)
    const float* xb = x + (size_t)b * 786432u;

    // ---- Phase 0: cooperative f4 loads, channel-min -> bf16 bits into A ----
    #pragma unroll
    for (int it = 0; it < 7; ++it) {
        const int t = tid + 256 * it;
        if (t < 66 * 26) {
            const int k = t / 26, g = t - 26 * k;
            const int gh  = h0 + k;
            const bool rv = (unsigned)gh < 512u;
            const int ghc = gh < 0 ? 0 : (gh > 511 ? 511 : gh);
            const float* rowp = xb + (size_t)ghc * 512u;
            const int gw = w0c + 4 * g;
            float m0, m1, m2, m3;
            if (gw >= 0 && gw <= 508) {
                const float4 a = *(const float4*)(rowp + gw);
                const float4 q = *(const float4*)(rowp + gw + 262144);
                const float4 c = *(const float4*)(rowp + gw + 524288);
                m0 = fminf(a.x, fminf(q.x, c.x));
                m1 = fminf(a.y, fminf(q.y, c.y));
                m2 = fminf(a.z, fminf(q.z, c.z));
                m3 = fminf(a.w, fminf(q.w, c.w));
            } else {                              // image col edges (tx=0/7 only)
                float mm[4];
                #pragma unroll
                for (int e = 0; e < 4; ++e) {
                    const int gg = gw + e;
                    const int gc = gg < 0 ? 0 : (gg > 511 ? 511 : gg);
                    mm[e] = ((unsigned)gg < 512u)
                          ? fminf(rowp[gc], fminf(rowp[gc + 262144], rowp[gc + 524288]))
                          : 1.0f;                 // col pad: min-neutral (x < 1)
                }
                m0 = mm[0]; m1 = mm[1]; m2 = mm[2]; m3 = mm[3];
            }
            if (!rv) { m0 = m1 = m2 = m3 = 1.0f; } // row pad: min-neutral
            uint2 pk;
            pk.x = (unsigned)f2b(m0) | ((unsigned)f2b(m1) << 16);
            pk.y = (unsigned)f2b(m2) | ((unsigned)f2b(m3) << 16);
            *(uint2*)&A[k * AST + 4 * g] = pk;
        }
    }
    __syncthreads();

    // ---- Phase V: vertical sliding-35 min (int mins on bf16 bits), straight-line ----
    if (tid < 196) {
        const int q = (tid >= 98) ? 1 : 0;
        const int j = tid - 98 * q;
        const int base = (16 * q) * AST + 3 + j;  // region col j = A col j+3
        int w[50];
        #pragma unroll
        for (int i = 0; i < 50; ++i) w[i] = A[base + AST * i];
        __builtin_amdgcn_sched_barrier(0);        // loads stay batched ABOVE the chain
        #pragma unroll
        for (int i = 0; i <= 48; ++i) w[i] = min(w[i], w[i + 1]);
        #pragma unroll
        for (int i = 0; i <= 46; ++i) w[i] = min(w[i], w[i + 2]);
        #pragma unroll
        for (int i = 0; i <= 42; ++i) w[i] = min(w[i], w[i + 4]);
        #pragma unroll
        for (int i = 0; i <= 34; ++i) w[i] = min(w[i], w[i + 8]);
        #pragma unroll
        for (int i = 0; i <= 18; ++i) w[i] = min(w[i], w[i + 16]);
        #pragma unroll
        for (int k = 0; k < 16; ++k)
            B[(16 * q + k) * BST + j] = (unsigned short)min(w[k], w[k + 3]);
    }
    __syncthreads();

    // ---- Phase H: horizontal sliding-35 min + sum(1-min); 128 straight-line tasks ----
    float s = 0.0f;
    if (tid < 128) {
        const int r = tid >> 2, c = tid & 3;      // out row r, 16-col chunk c
        const int base = r * BST + 16 * c;        // halfword idx, even -> u32-aligned
        int h[52];
        #pragma unroll
        for (int k = 0; k < 26; ++k) {            // conflict-free (BST=102: odd dword stride)
            const unsigned int u = *(const unsigned int*)&B[base + 2 * k];
            h[2 * k]     = (int)(u & 0xFFFFu);
            h[2 * k + 1] = (int)(u >> 16);
        }
        __builtin_amdgcn_sched_barrier(0);        // keep the 26 reads batched
        #pragma unroll
        for (int i = 0; i <= 48; ++i) h[i] = min(h[i], h[i + 1]);
        #pragma unroll
        for (int i = 0; i <= 46; ++i) h[i] = min(h[i], h[i + 2]);
        #pragma unroll
        for (int i = 0; i <= 42; ++i) h[i] = min(h[i], h[i + 4]);
        #pragma unroll
        for (int i = 0; i <= 34; ++i) h[i] = min(h[i], h[i + 8]);
        #pragma unroll
        for (int i = 0; i <= 18; ++i) h[i] = min(h[i], h[i + 16]);
        #pragma unroll
        for (int k = 0; k < 16; ++k) {
            const int mb = min(h[k], h[k + 3]);   // 35-min bits for out col 16c+k
            s += 1.0f - __uint_as_float((unsigned)mb << 16);   // dc >= 0
        }
    }

    // ---- block reduction + last-block finish (the ONLY change vs R7) ----
    #pragma unroll
    for (int off = 32; off; off >>= 1) s += __shfl_down(s, off);
    if ((tid & 63) == 0) red[tid >> 6] = s;
    __syncthreads();
    if (tid == 0) {
        const float bs = red[0] + red[1] + red[2] + red[3];
        __hip_atomic_store(&part[bid], bs, __ATOMIC_RELEASE, __HIP_MEMORY_SCOPE_AGENT);
        const int old = __hip_atomic_fetch_add(cnt, 1, __ATOMIC_ACQ_REL,
                                               __HIP_MEMORY_SCOPE_AGENT);
        last = (old == NB - 1);
    }
    __syncthreads();

    if (last) {                                   // exactly one block reaches here
        float s2 = 0.0f;
        #pragma unroll
        for (int i = 0; i < 8; ++i)               // fixed order -> deterministic
            s2 += __hip_atomic_load(&part[tid + NT * i], __ATOMIC_ACQUIRE,
                                    __HIP_MEMORY_SCOPE_AGENT);
        #pragma unroll
        for (int off = 32; off; off >>= 1) s2 += __shfl_down(s2, off);
        if ((tid & 63) == 0) red[tid >> 6] = s2;
        __syncthreads();
        if (tid == 0)
            out[0] = -(red[0] + red[1] + red[2] + red[3]) * (1.0f / 4194304.0f);
    }
}

extern "C" void kernel_launch(void* const* d_in, const int* in_sizes, int n_in,
                              void* d_out, int out_size, void* d_ws, size_t ws_size,
                              hipStream_t stream) {
    const float* x = (const float*)d_in[0];
    float* out  = (float*)d_out;
    int*   cnt  = (int*)d_ws;                    // arrival counter
    float* part = (float*)((char*)d_ws + 256);   // 2048 partials, rewritten every call

    hipMemsetAsync(d_ws, 0, 4, stream);          // zero counter (memset node)
    hipLaunchKernelGGL(dark_fused, dim3(NB), dim3(NT), 0, stream, x, cnt, part, out);
}

// Round 10
// 23.126 us; speedup vs baseline: 4.1644x; 4.1644x over previous
//
#include <hip/hip_runtime.h>
#include <math.h>

#define NT 256
#define NB 2048
#define AST 104        // A row stride (halfwords) = 52 dwords; col a <-> image col w0c+a
#define BST 102        // B row stride (halfwords) = 51 dwords; B col = A col (2..101 used)

// f32 -> bf16 bits, round-to-nearest-even (inputs finite, >= 0)
__device__ __forceinline__ unsigned short f2b(float f) {
    unsigned int u = __float_as_uint(f);
    u += 0x7FFFu + ((u >> 16) & 1u);
    return (unsigned short)(u >> 16);
}

// packed unsigned 16-bit min (elementwise on two bf16-bit lanes; valid: values >= 0)
__device__ __forceinline__ unsigned pkmin(unsigned a, unsigned b) {
    unsigned d;
    asm("v_pk_min_u16 %0, %1, %2" : "=v"(d) : "v"(a), "v"(b));
    return d;
}

__global__ __launch_bounds__(NT, 5)
void dark_main(const float* __restrict__ x, float* __restrict__ part) {
    __shared__ unsigned short A[66 * AST];   // 13728 B: bf16 bits of m=min_c(x); pad=1.0
    __shared__ unsigned short B[32 * BST];   // 6528 B: bf16 bits of vertical 35-min
    __shared__ float red[4];                 // ~20.3 KB total -> 5 blocks/CU

    const int tid = threadIdx.x;
    const int bid = blockIdx.x;
    // XCD swizzle (R7): XCD k -> 256 consecutive tiles = images 2k,2k+1
    const int swz = (bid & 7) * 256 + (bid >> 3);
    const int b   = swz >> 7;                // 128 tiles per image (16 ty x 8 tx)
    const int rem = swz & 127;
    const int ty  = rem >> 3;                // 32-row bands
    const int tx  = rem & 7;                 // 64-col bands
    const int h0  = ty * 32 - 17;            // region row k <-> image row h0+k, k in [0,66)
    const int w0c = tx * 64 - 20;            // A col a <-> image col w0c+a (f4-aligned)
    const float* xb = x + (size_t)b * 786432u;

    // ---- Phase 0 (unchanged from R7): f4 loads, channel-min -> bf16 bits into A ----
    #pragma unroll
    for (int it = 0; it < 7; ++it) {
        const int t = tid + 256 * it;
        if (t < 66 * 26) {
            const int k = t / 26, g = t - 26 * k;
            const int gh  = h0 + k;
            const bool rv = (unsigned)gh < 512u;
            const int ghc = gh < 0 ? 0 : (gh > 511 ? 511 : gh);
            const float* rowp = xb + (size_t)ghc * 512u;
            const int gw = w0c + 4 * g;
            float m0, m1, m2, m3;
            if (gw >= 0 && gw <= 508) {
                const float4 a = *(const float4*)(rowp + gw);
                const float4 q = *(const float4*)(rowp + gw + 262144);
                const float4 c = *(const float4*)(rowp + gw + 524288);
                m0 = fminf(a.x, fminf(q.x, c.x));
                m1 = fminf(a.y, fminf(q.y, c.y));
                m2 = fminf(a.z, fminf(q.z, c.z));
                m3 = fminf(a.w, fminf(q.w, c.w));
            } else {                              // image col edges (tx=0/7 only)
                float mm[4];
                #pragma unroll
                for (int e = 0; e < 4; ++e) {
                    const int gg = gw + e;
                    const int gc = gg < 0 ? 0 : (gg > 511 ? 511 : gg);
                    mm[e] = ((unsigned)gg < 512u)
                          ? fminf(rowp[gc], fminf(rowp[gc + 262144], rowp[gc + 524288]))
                          : 1.0f;                 // col pad: min-neutral (x < 1)
                }
                m0 = mm[0]; m1 = mm[1]; m2 = mm[2]; m3 = mm[3];
            }
            if (!rv) { m0 = m1 = m2 = m3 = 1.0f; } // row pad: min-neutral
            uint2 pk;
            pk.x = (unsigned)f2b(m0) | ((unsigned)f2b(m1) << 16);
            pk.y = (unsigned)f2b(m2) | ((unsigned)f2b(m3) << 16);
            *(uint2*)&A[k * AST + 4 * g] = pk;
        }
    }
    __syncthreads();

    // ---- Phase V: packed col-pair sliding-35 min (v_pk_min_u16) ----
    // Wave w owns out-row chunk 8w..8w+7; lanes 0..49 own A dword-col p=lane+1
    // (= A halfword cols 2p,2p+1; covers A cols 2..101 >= needed 3..100).
    {
        const int qc   = tid >> 6;               // wave id = 8-row chunk
        const int lane = tid & 63;
        if (lane < 50) {
            const int p = lane + 1;
            const unsigned* Au = (const unsigned*)A;     // row stride 52 dwords
            const int base = (8 * qc) * 52 + p;
            unsigned w[42];
            #pragma unroll
            for (int i = 0; i < 42; ++i) w[i] = Au[base + 52 * i];
            __builtin_amdgcn_sched_barrier(0);   // keep the 42 reads batched
            #pragma unroll
            for (int i = 0; i <= 40; ++i) w[i] = pkmin(w[i], w[i + 1]);
            #pragma unroll
            for (int i = 0; i <= 38; ++i) w[i] = pkmin(w[i], w[i + 2]);
            #pragma unroll
            for (int i = 0; i <= 34; ++i) w[i] = pkmin(w[i], w[i + 4]);
            #pragma unroll
            for (int i = 0; i <= 26; ++i) w[i] = pkmin(w[i], w[i + 8]);
            #pragma unroll
            for (int i = 0; i <= 10; ++i) w[i] = pkmin(w[i], w[i + 16]);
            unsigned* Bu = (unsigned*)B;                 // row stride 51 dwords
            #pragma unroll
            for (int k = 0; k < 8; ++k)                  // out row 8qc+k = min rows ..+34
                Bu[(8 * qc + k) * 51 + p] = pkmin(w[k], w[k + 3]);
        }
    }
    __syncthreads();

    // ---- Phase H: 256 tasks (100% lanes): row r, 8-col chunk c ----
    // h[i] = B col 8c+2+i; out col o=8c+k (window A cols o+3..o+37) = h[k+1..k+35].
    float s = 0.0f;
    {
        const int r = tid >> 3, c = tid & 7;
        const unsigned* Bu = (const unsigned*)B;
        const int base = r * 51 + 4 * c + 1;     // dword idx of B col 8c+2 (even col)
        int h[44];
        #pragma unroll
        for (int i = 0; i < 22; ++i) {           // banks exactly 2-way across wave (free)
            const unsigned u = Bu[base + i];
            h[2 * i]     = (int)(u & 0xFFFFu);
            h[2 * i + 1] = (int)(u >> 16);
        }
        __builtin_amdgcn_sched_barrier(0);       // keep the 22 reads batched
        #pragma unroll
        for (int i = 0; i <= 42; ++i) h[i] = min(h[i], h[i + 1]);
        #pragma unroll
        for (int i = 0; i <= 40; ++i) h[i] = min(h[i], h[i + 2]);
        #pragma unroll
        for (int i = 0; i <= 36; ++i) h[i] = min(h[i], h[i + 4]);
        #pragma unroll
        for (int i = 0; i <= 28; ++i) h[i] = min(h[i], h[i + 8]);
        #pragma unroll
        for (int i = 0; i <= 12; ++i) h[i] = min(h[i], h[i + 16]);
        #pragma unroll
        for (int k = 0; k < 8; ++k) {
            const int mb = min(h[k + 1], h[k + 4]);      // 35-min bits, out col 8c+k
            s += 1.0f - __uint_as_float((unsigned)mb << 16);   // dc >= 0
        }
    }

    // ---- block reduction (deterministic) ----
    #pragma unroll
    for (int off = 32; off; off >>= 1) s += __shfl_down(s, off);
    if ((tid & 63) == 0) red[tid >> 6] = s;
    __syncthreads();
    if (tid == 0) part[bid] = red[0] + red[1] + red[2] + red[3];
}

__global__ void dark_reduce(const float* __restrict__ part, float* __restrict__ out) {
    const int tid = threadIdx.x;
    float s = 0.0f;
    #pragma unroll
    for (int i = 0; i < 8; ++i) s += part[tid + 256 * i];   // fixed order
    #pragma unroll
    for (int off = 32; off; off >>= 1) s += __shfl_down(s, off);
    __shared__ float w[4];
    if ((tid & 63) == 0) w[tid >> 6] = s;
    __syncthreads();
    if (tid == 0)
        out[0] = -(w[0] + w[1] + w[2] + w[3]) * (1.0f / 4194304.0f);  // -mean
}

extern "C" void kernel_launch(void* const* d_in, const int* in_sizes, int n_in,
                              void* d_out, int out_size, void* d_ws, size_t ws_size,
                              hipStream_t stream) {
    const float* x = (const float*)d_in[0];
    float* out  = (float*)d_out;
    float* part = (float*)d_ws;                  // 2048 floats, fully rewritten each call

    hipLaunchKernelGGL(dark_main,   dim3(NB), dim3(NT), 0, stream, x, part);
    hipLaunchKernelGGL(dark_reduce, dim3(1),  dim3(NT), 0, stream, part, out);
}

// Round 11
// 22.171 us; speedup vs baseline: 4.3438x; 1.0431x over previous
//
#include <hip/hip_runtime.h>
#include <math.h>

#define NT 256
#define NB 1024
#define AST 104        // A row stride (halfwords) = 52 dwords; col a <-> image col w0c+a
#define BST 102        // B row stride (halfwords) = 51 dwords; B col = A col (2..101 used)

// f32 -> bf16 bits, round-to-nearest-even (inputs finite, >= 0)
__device__ __forceinline__ unsigned short f2b(float f) {
    unsigned int u = __float_as_uint(f);
    u += 0x7FFFu + ((u >> 16) & 1u);
    return (unsigned short)(u >> 16);
}

// packed unsigned 16-bit min (elementwise on two bf16-bit lanes; valid: values >= 0)
__device__ __forceinline__ unsigned pkmin(unsigned a, unsigned b) {
    unsigned d;
    asm("v_pk_min_u16 %0, %1, %2" : "=v"(d) : "v"(a), "v"(b));
    return d;
}

// Vertical sliding-35 min, packed col-pair p (dword), out rows 8qc..8qc+7
__device__ __forceinline__ void vtask(const unsigned* __restrict__ Au,
                                      unsigned* __restrict__ Bu, int qc, int p) {
    const int base = (8 * qc) * 52 + p;
    unsigned w[42];
    #pragma unroll
    for (int i = 0; i < 42; ++i) w[i] = Au[base + 52 * i];
    __builtin_amdgcn_sched_barrier(0);           // keep the 42 reads batched
    #pragma unroll
    for (int i = 0; i <= 40; ++i) w[i] = pkmin(w[i], w[i + 1]);
    #pragma unroll
    for (int i = 0; i <= 38; ++i) w[i] = pkmin(w[i], w[i + 2]);
    #pragma unroll
    for (int i = 0; i <= 34; ++i) w[i] = pkmin(w[i], w[i + 4]);
    #pragma unroll
    for (int i = 0; i <= 26; ++i) w[i] = pkmin(w[i], w[i + 8]);
    #pragma unroll
    for (int i = 0; i <= 10; ++i) w[i] = pkmin(w[i], w[i + 16]);
    #pragma unroll
    for (int k = 0; k < 8; ++k)                  // out row 8qc+k = min rows ..+34
        Bu[(8 * qc + k) * 51 + p] = pkmin(w[k], w[k + 3]);
}

// Horizontal sliding-35 min + partial sum for out row r, 8-col chunk c
__device__ __forceinline__ float htask(const unsigned* __restrict__ Bu, int r, int c) {
    const int base = r * 51 + 4 * c + 1;         // dword idx of B halfword col 8c+2
    int h[44];
    #pragma unroll
    for (int i = 0; i < 22; ++i) {               // banks 2-way across wave (free)
        const unsigned u = Bu[base + i];
        h[2 * i]     = (int)(u & 0xFFFFu);
        h[2 * i + 1] = (int)(u >> 16);
    }
    __builtin_amdgcn_sched_barrier(0);           // keep the 22 reads batched
    #pragma unroll
    for (int i = 0; i <= 42; ++i) h[i] = min(h[i], h[i + 1]);
    #pragma unroll
    for (int i = 0; i <= 40; ++i) h[i] = min(h[i], h[i + 2]);
    #pragma unroll
    for (int i = 0; i <= 36; ++i) h[i] = min(h[i], h[i + 4]);
    #pragma unroll
    for (int i = 0; i <= 28; ++i) h[i] = min(h[i], h[i + 8]);
    #pragma unroll
    for (int i = 0; i <= 12; ++i) h[i] = min(h[i], h[i + 16]);
    float s = 0.0f;
    #pragma unroll
    for (int k = 0; k < 8; ++k) {
        const int mb = min(h[k + 1], h[k + 4]);  // 35-min bits, out col 8c+k
        s += 1.0f - __uint_as_float((unsigned)mb << 16);   // dc >= 0
    }
    return s;
}

__global__ __launch_bounds__(NT, 4)
void dark_main(const float* __restrict__ x, float* __restrict__ part) {
    __shared__ unsigned short A[98 * AST];   // 20384 B: bf16 bits of m=min_c(x); pad=1.0
    __shared__ unsigned short B[64 * BST];   // 13056 B: vertical 35-min bits
    __shared__ float red[4];                 // ~33.5 KB total -> 4 blocks/CU

    const int tid = threadIdx.x;
    const int bid = blockIdx.x;
    // XCD swizzle: XCD k -> 128 consecutive tiles = images 2k, 2k+1
    const int swz = (bid & 7) * 128 + (bid >> 3);
    const int b   = swz >> 6;                // 64 tiles per image (8x8 of 64x64)
    const int ty  = (swz >> 3) & 7;
    const int tx  = swz & 7;
    const int h0  = ty * 64 - 17;            // region row k <-> image row h0+k, k in [0,98)
    const int w0c = tx * 64 - 20;            // A col a <-> image col w0c+a (f4-aligned)
    const float* xb = x + (size_t)b * 786432u;

    // ---- Phase 0: cooperative f4 loads, channel-min -> bf16 bits into A ----
    #pragma unroll
    for (int it = 0; it < 10; ++it) {
        const int t = tid + 256 * it;
        if (t < 98 * 26) {
            const int k = t / 26, g = t - 26 * k;
            const int gh  = h0 + k;
            const bool rv = (unsigned)gh < 512u;
            const int ghc = gh < 0 ? 0 : (gh > 511 ? 511 : gh);
            const float* rowp = xb + (size_t)ghc * 512u;
            const int gw = w0c + 4 * g;
            float m0, m1, m2, m3;
            if (gw >= 0 && gw <= 508) {
                const float4 a = *(const float4*)(rowp + gw);
                const float4 q = *(const float4*)(rowp + gw + 262144);
                const float4 c = *(const float4*)(rowp + gw + 524288);
                m0 = fminf(a.x, fminf(q.x, c.x));
                m1 = fminf(a.y, fminf(q.y, c.y));
                m2 = fminf(a.z, fminf(q.z, c.z));
                m3 = fminf(a.w, fminf(q.w, c.w));
            } else {                              // image col edges (tx=0/7 only)
                float mm[4];
                #pragma unroll
                for (int e = 0; e < 4; ++e) {
                    const int gg = gw + e;
                    const int gc = gg < 0 ? 0 : (gg > 511 ? 511 : gg);
                    mm[e] = ((unsigned)gg < 512u)
                          ? fminf(rowp[gc], fminf(rowp[gc + 262144], rowp[gc + 524288]))
                          : 1.0f;                 // col pad: min-neutral (x < 1)
                }
                m0 = mm[0]; m1 = mm[1]; m2 = mm[2]; m3 = mm[3];
            }
            if (!rv) { m0 = m1 = m2 = m3 = 1.0f; } // row pad: min-neutral
            uint2 pk;
            pk.x = (unsigned)f2b(m0) | ((unsigned)f2b(m1) << 16);
            pk.y = (unsigned)f2b(m2) | ((unsigned)f2b(m3) << 16);
            *(uint2*)&A[k * AST + 4 * g] = pk;
        }
    }
    __syncthreads();

    // ---- Phase V: packed col-pair sliding-35 min; 8 chunks over 2 passes ----
    // Wave w, lanes 0..49 own A dword-col p = lane+1 (A halfword cols 2..101).
    {
        const int wv   = tid >> 6;
        const int lane = tid & 63;
        const unsigned* Au = (const unsigned*)A;   // row stride 52 dwords
        unsigned* Bu = (unsigned*)B;               // row stride 51 dwords
        const int p = lane + 1;
        if (lane < 50) vtask(Au, Bu, wv, p);       // out rows 0..31
        if (lane < 50) vtask(Au, Bu, wv + 4, p);   // out rows 32..63
    }
    __syncthreads();

    // ---- Phase H: 512 tasks, 2 per thread (100% lanes) ----
    float s = 0.0f;
    {
        const unsigned* Bu = (const unsigned*)B;
        s += htask(Bu, tid >> 3, tid & 7);              // rows 0..31
        s += htask(Bu, 32 + (tid >> 3), tid & 7);       // rows 32..63
    }

    // ---- block reduction (deterministic) ----
    #pragma unroll
    for (int off = 32; off; off >>= 1) s += __shfl_down(s, off);
    if ((tid & 63) == 0) red[tid >> 6] = s;
    __syncthreads();
    if (tid == 0) part[bid] = red[0] + red[1] + red[2] + red[3];
}

__global__ void dark_reduce(const float* __restrict__ part, float* __restrict__ out) {
    const int tid = threadIdx.x;
    float s = 0.0f;
    #pragma unroll
    for (int i = 0; i < 4; ++i) s += part[tid + 256 * i];   // fixed order
    #pragma unroll
    for (int off = 32; off; off >>= 1) s += __shfl_down(s, off);
    __shared__ float w[4];
    if ((tid & 63) == 0) w[tid >> 6] = s;
    __syncthreads();
    if (tid == 0)
        out[0] = -(w[0] + w[1] + w[2] + w[3]) * (1.0f / 4194304.0f);  // -mean
}

extern "C" void kernel_launch(void* const* d_in, const int* in_sizes, int n_in,
                              void* d_out, int out_size, void* d_ws, size_t ws_size,
                              hipStream_t stream) {
    const float* x = (const float*)d_in[0];
    float* out  = (float*)d_out;
    float* part = (float*)d_ws;                  // 1024 floats, fully rewritten each call

    hipLaunchKernelGGL(dark_main,   dim3(NB), dim3(NT), 0, stream, x, part);
    hipLaunchKernelGGL(dark_reduce, dim3(1),  dim3(NT), 0, stream, part, out);
}

// Round 12
// 19.852 us; speedup vs baseline: 4.8510x; 1.1168x over previous
//
#include <hip/hip_runtime.h>
#include <math.h>

#define NT 256
#define NB 1024
#define AST 104        // A row stride (halfwords) = 52 dwords; col a <-> image col w0c+a
#define BST 102        // B row stride (halfwords) = 51 dwords; B col = A col (2..101 used)

// f32 -> bf16 bits, round-to-nearest-even (inputs finite, >= 0)
__device__ __forceinline__ unsigned short f2b(float f) {
    unsigned int u = __float_as_uint(f);
    u += 0x7FFFu + ((u >> 16) & 1u);
    return (unsigned short)(u >> 16);
}

// packed unsigned 16-bit min (elementwise on two bf16-bit lanes; valid: values >= 0)
__device__ __forceinline__ unsigned pkmin(unsigned a, unsigned b) {
    unsigned d;
    asm("v_pk_min_u16 %0, %1, %2" : "=v"(d) : "v"(a), "v"(b));
    return d;
}

// Vertical sliding-35 min, packed col-pair p (dword), out rows 8qc..8qc+7
__device__ __forceinline__ void vtask(const unsigned* __restrict__ Au,
                                      unsigned* __restrict__ Bu, int qc, int p) {
    const int base = (8 * qc) * 52 + p;
    unsigned w[42];
    #pragma unroll
    for (int i = 0; i < 42; ++i) w[i] = Au[base + 52 * i];
    __builtin_amdgcn_sched_barrier(0);           // keep the 42 reads batched
    #pragma unroll
    for (int i = 0; i <= 40; ++i) w[i] = pkmin(w[i], w[i + 1]);
    #pragma unroll
    for (int i = 0; i <= 38; ++i) w[i] = pkmin(w[i], w[i + 2]);
    #pragma unroll
    for (int i = 0; i <= 34; ++i) w[i] = pkmin(w[i], w[i + 4]);
    #pragma unroll
    for (int i = 0; i <= 26; ++i) w[i] = pkmin(w[i], w[i + 8]);
    #pragma unroll
    for (int i = 0; i <= 10; ++i) w[i] = pkmin(w[i], w[i + 16]);
    #pragma unroll
    for (int k = 0; k < 8; ++k)                  // out row 8qc+k = min rows ..+34
        Bu[(8 * qc + k) * 51 + p] = pkmin(w[k], w[k + 3]);
}

// Horizontal sliding-35 min + partial sum for out row r, 8-col chunk c
__device__ __forceinline__ float htask(const unsigned* __restrict__ Bu, int r, int c) {
    const int base = r * 51 + 4 * c + 1;         // dword idx of B halfword col 8c+2
    int h[44];
    #pragma unroll
    for (int i = 0; i < 22; ++i) {               // banks 2-way across wave (free)
        const unsigned u = Bu[base + i];
        h[2 * i]     = (int)(u & 0xFFFFu);
        h[2 * i + 1] = (int)(u >> 16);
    }
    __builtin_amdgcn_sched_barrier(0);           // keep the 22 reads batched
    #pragma unroll
    for (int i = 0; i <= 42; ++i) h[i] = min(h[i], h[i + 1]);
    #pragma unroll
    for (int i = 0; i <= 40; ++i) h[i] = min(h[i], h[i + 2]);
    #pragma unroll
    for (int i = 0; i <= 36; ++i) h[i] = min(h[i], h[i + 4]);
    #pragma unroll
    for (int i = 0; i <= 28; ++i) h[i] = min(h[i], h[i + 8]);
    #pragma unroll
    for (int i = 0; i <= 12; ++i) h[i] = min(h[i], h[i + 16]);
    float s = 0.0f;
    #pragma unroll
    for (int k = 0; k < 8; ++k) {
        const int mb = min(h[k + 1], h[k + 4]);  // 35-min bits, out col 8c+k
        s += 1.0f - __uint_as_float((unsigned)mb << 16);   // dc >= 0
    }
    return s;
}

__global__ __launch_bounds__(NT, 4)
void dark_main(const float* __restrict__ x, float* __restrict__ part) {
    __shared__ unsigned short A[98 * AST];   // 20384 B: bf16 bits of m=min_c(x); pad=1.0
    __shared__ unsigned short B[64 * BST];   // 13056 B: vertical 35-min bits
    __shared__ float red[4];                 // ~33.5 KB total -> 4 blocks/CU

    const int tid = threadIdx.x;
    const int bid = blockIdx.x;
    // XCD swizzle: XCD k -> 128 consecutive tiles = images 2k, 2k+1
    const int swz = (bid & 7) * 128 + (bid >> 3);
    const int b   = swz >> 6;                // 64 tiles per image (8x8 of 64x64)
    const int ty  = (swz >> 3) & 7;
    const int tx  = swz & 7;
    const int h0  = ty * 64 - 17;            // region row k <-> image row h0+k, k in [0,98)
    const int w0c = tx * 64 - 20;            // A col a <-> image col w0c+a (f4-aligned)
    const float* xb = x + (size_t)b * 786432u;

    // ---- Phase 0: BRANCHLESS deep-batched loads (15 dwordx4 in flight) ----
    // Key fact: w0c % 4 == 0 and width 512 % 4 == 0 => every f4-group is fully
    // in-bounds or fully pad. Loads use clamped addrs (always legal); pad via select.
    #pragma unroll
    for (int blk = 0; blk < 2; ++blk) {
        float4 va[5], vb[5], vc[5];
        int kr[5], gr[5];
        bool ok[5];
        #pragma unroll
        for (int i = 0; i < 5; ++i) {                 // issue 15 loads back-to-back
            const int t = tid + 256 * (5 * blk + i);  // t < 2560; A has 2548 slots
            const int k = t / 26, g = t - 26 * k;
            const int gh  = h0 + k;
            const int ghc = gh < 0 ? 0 : (gh > 511 ? 511 : gh);
            const int gw  = w0c + 4 * g;
            const int gwc = gw < 0 ? 0 : (gw > 508 ? 508 : gw);
            const float* p = xb + (size_t)ghc * 512u + gwc;
            ok[i] = ((unsigned)gh < 512u) && ((unsigned)gw < 512u);
            kr[i] = k; gr[i] = g;
            va[i] = *(const float4*)p;
            vb[i] = *(const float4*)(p + 262144);
            vc[i] = *(const float4*)(p + 524288);
        }
        __builtin_amdgcn_sched_barrier(0);            // loads stay batched above
        #pragma unroll
        for (int i = 0; i < 5; ++i) {                 // process + LDS store
            const int t = tid + 256 * (5 * blk + i);
            if (t < 98 * 26) {                        // only final iter partially off
                float m0 = fminf(va[i].x, fminf(vb[i].x, vc[i].x));
                float m1 = fminf(va[i].y, fminf(vb[i].y, vc[i].y));
                float m2 = fminf(va[i].z, fminf(vb[i].z, vc[i].z));
                float m3 = fminf(va[i].w, fminf(vb[i].w, vc[i].w));
                if (!ok[i]) { m0 = m1 = m2 = m3 = 1.0f; }   // pad: min-neutral
                uint2 pk;
                pk.x = (unsigned)f2b(m0) | ((unsigned)f2b(m1) << 16);
                pk.y = (unsigned)f2b(m2) | ((unsigned)f2b(m3) << 16);
                *(uint2*)&A[kr[i] * AST + 4 * gr[i]] = pk;
            }
        }
    }
    __syncthreads();

    // ---- Phase V: packed col-pair sliding-35 min; 8 chunks over 2 passes ----
    // Wave w, lanes 0..49 own A dword-col p = lane+1 (A halfword cols 2..101).
    {
        const int wv   = tid >> 6;
        const int lane = tid & 63;
        const unsigned* Au = (const unsigned*)A;   // row stride 52 dwords
        unsigned* Bu = (unsigned*)B;               // row stride 51 dwords
        const int p = lane + 1;
        if (lane < 50) vtask(Au, Bu, wv, p);       // out rows 0..31
        if (lane < 50) vtask(Au, Bu, wv + 4, p);   // out rows 32..63
    }
    __syncthreads();

    // ---- Phase H: 512 tasks, 2 per thread (100% lanes) ----
    float s = 0.0f;
    {
        const unsigned* Bu = (const unsigned*)B;
        s += htask(Bu, tid >> 3, tid & 7);              // rows 0..31
        s += htask(Bu, 32 + (tid >> 3), tid & 7);       // rows 32..63
    }

    // ---- block reduction (deterministic) ----
    #pragma unroll
    for (int off = 32; off; off >>= 1) s += __shfl_down(s, off);
    if ((tid & 63) == 0) red[tid >> 6] = s;
    __syncthreads();
    if (tid == 0) part[bid] = red[0] + red[1] + red[2] + red[3];
}

__global__ void dark_reduce(const float* __restrict__ part, float* __restrict__ out) {
    const int tid = threadIdx.x;
    float s = 0.0f;
    #pragma unroll
    for (int i = 0; i < 4; ++i) s += part[tid + 256 * i];   // fixed order
    #pragma unroll
    for (int off = 32; off; off >>= 1) s += __shfl_down(s, off);
    __shared__ float w[4];
    if ((tid & 63) == 0) w[tid >> 6] = s;
    __syncthreads();
    if (tid == 0)
        out[0] = -(w[0] + w[1] + w[2] + w[3]) * (1.0f / 4194304.0f);  // -mean
}

extern "C" void kernel_launch(void* const* d_in, const int* in_sizes, int n_in,
                              void* d_out, int out_size, void* d_ws, size_t ws_size,
                              hipStream_t stream) {
    const float* x = (const float*)d_in[0];
    float* out  = (float*)d_out;
    float* part = (float*)d_ws;                  // 1024 floats, fully rewritten each call

    hipLaunchKernelGGL(dark_main,   dim3(NB), dim3(NT), 0, stream, x, part);
    hipLaunchKernelGGL(dark_reduce, dim3(1),  dim3(NT), 0, stream, part, out);
}